// Round 6
// baseline (44.010 us; speedup 1.0000x reference)
//
#include <hip/hip_runtime.h>
#include <hip/hip_bf16.h>

#define NB      16          // nodes per wave-tile
#define THREADS 256         // 4 independent waves per block

// d_ws layout (float offsets)
#define WS_CST4   0         // 64 x float4 (a*g, b*g, c*g, bet)
#define WS_QUAD   256       // 6 floats: E[a2],E[b2],E[ab],E[ac],E[bc],E[c2]+eps
#define WS_DISC   272       // 18*128 floats: b2 + Ei[a]+Et[b]+Etc[c]
#define WS_W2     2576      // 16 frags * 64 lanes * 16B (bf16 B-fragments)

typedef float f32x4  __attribute__((ext_vector_type(4)));
typedef short bf16x8 __attribute__((ext_vector_type(8)));

static __device__ __forceinline__ unsigned f2bf(float f) {
    __hip_bfloat16 h = __float2bfloat16(f);   // RNE
    return (unsigned)__builtin_bit_cast(unsigned short, h);
}

__global__ __launch_bounds__(THREADS)
void lane_setup_kernel(const float* __restrict__ W1, const float* __restrict__ b1,
                       const float* __restrict__ gam, const float* __restrict__ bet,
                       const float* __restrict__ W2, const float* __restrict__ b2,
                       const float* __restrict__ Ei, const float* __restrict__ Et,
                       const float* __restrict__ Etc, float* __restrict__ ws)
{
    const int tid = threadIdx.x, lane = tid & 63, wv = tid >> 6;

    if (wv == 0) {
        float wx = W1[lane], wy = W1[64 + lane], bb = b1[lane];
        float sx = wx, sy = wy, sb = bb;
        #pragma unroll
        for (int m = 1; m < 64; m <<= 1) {
            sx += __shfl_xor(sx, m, 64);
            sy += __shfl_xor(sy, m, 64);
            sb += __shfl_xor(sb, m, 64);
        }
        float a = wx - sx * (1.f / 64.f);
        float b = wy - sy * (1.f / 64.f);
        float c = bb - sb * (1.f / 64.f);
        float p0 = a * a, p1 = b * b, p2 = a * b, p3 = a * c, p4 = b * c, p5 = c * c;
        #pragma unroll
        for (int m = 1; m < 64; m <<= 1) {
            p0 += __shfl_xor(p0, m, 64); p1 += __shfl_xor(p1, m, 64);
            p2 += __shfl_xor(p2, m, 64); p3 += __shfl_xor(p3, m, 64);
            p4 += __shfl_xor(p4, m, 64); p5 += __shfl_xor(p5, m, 64);
        }
        float g = gam[lane];
        ((float4*)(ws + WS_CST4))[lane] = make_float4(a * g, b * g, c * g, bet[lane]);
        if (lane == 0) {
            ws[WS_QUAD + 0] = p0 * (1.f / 64.f);
            ws[WS_QUAD + 1] = p1 * (1.f / 64.f);
            ws[WS_QUAD + 2] = p2 * (1.f / 64.f);
            ws[WS_QUAD + 3] = p3 * (1.f / 64.f);
            ws[WS_QUAD + 4] = p4 * (1.f / 64.f);
            ws[WS_QUAD + 5] = p5 * (1.f / 64.f) + 1e-5f;   // fold LN eps
        }
    }

    // W2 bf16 fragments, exact per-lane MFMA-B layout
    {
        uint4* dst = (uint4*)(ws + WS_W2);
        #pragma unroll
        for (int f = wv * 4; f < wv * 4 + 4; ++f) {
            int c = f >> 1, kt = f & 1;
            int col = c * 16 + (lane & 15);
            int k0  = kt * 32 + (lane >> 4) * 8;
            unsigned w[4];
            #pragma unroll
            for (int j = 0; j < 4; ++j) {
                unsigned lo = f2bf(W2[(k0 + 2 * j) * 128 + col]);
                unsigned hi = f2bf(W2[(k0 + 2 * j + 1) * 128 + col]);
                w[j] = (hi << 16) | lo;
            }
            dst[f * 64 + lane] = make_uint4(w[0], w[1], w[2], w[3]);
        }
    }

    // disc table: all 18 (a,b,c) combos, b2 folded in
    for (int i = tid; i < 18 * 128; i += THREADS) {
        int combo = i >> 7, col = i & 127;
        int ai = combo / 6; int r = combo - ai * 6; int bi = r >> 1; int ci = r & 1;
        ws[WS_DISC + i] = b2[col] + Ei[ai * 128 + col] + Et[bi * 128 + col] + Etc[ci * 128 + col];
    }
}

__global__ __launch_bounds__(THREADS)
void lane_node_embed_mfma(const float* __restrict__ pos,      // [N,10,2]
                          const int*   __restrict__ idx_int,  // [N]
                          const int*   __restrict__ idx_turn, // [N]
                          const int*   __restrict__ idx_tc,   // [N]
                          const float* __restrict__ ws,
                          float* __restrict__ out,            // [N,128]
                          int n_nodes)
{
    const int tid  = threadIdx.x;
    const int lane = tid & 63;
    const int wv   = tid >> 6;
    const int tile = blockIdx.x * 4 + wv;     // one wave = one 16-node tile
    const int base = tile * NB;

    const int l15 = lane & 15;
    const int g   = lane >> 4;

    // LN quadratic constants (wave-uniform -> s_loads)
    const float qA = ws[WS_QUAD + 0], qB = ws[WS_QUAD + 1], qC = ws[WS_QUAD + 2];
    const float qD = ws[WS_QUAD + 3], qE = ws[WS_QUAD + 4], qF = ws[WS_QUAD + 5];

    // per-lane LN constants for this lane's 16 k-values:
    // k in {8g..8g+7} (kt0) and {32+8g..32+8g+7} (kt1)
    float4 cst[16];
    const float4* c4p = (const float4*)(ws + WS_CST4);
    #pragma unroll
    for (int j = 0; j < 8; ++j) {
        cst[j]     = c4p[g * 8 + j];
        cst[8 + j] = c4p[32 + g * 8 + j];
    }

    // all 8 B-coltiles in registers (prepacked, coalesced)
    const uint4* wfr = (const uint4*)(ws + WS_W2);
    bf16x8 Bfr[8][2];
    #pragma unroll
    for (int c = 0; c < 8; ++c)
        #pragma unroll
        for (int kt = 0; kt < 2; ++kt)
            Bfr[c][kt] = __builtin_bit_cast(bf16x8, wfr[(c * 2 + kt) * 64 + lane]);

    // ---- stash (ax, ay) for all 144 (node,p) pairs across 3 register slots:
    // slot s: lane (g,l15) owns (node=l15, p=s*4+g); p=8 lives in slot2 lanes g==0
    float axs[3], ays[3];
    #pragma unroll
    for (int s = 0; s < 3; ++s) {
        int p = s * 4 + g;
        float ax = 0.f, ay = 0.f;
        int gn = base + l15;
        if (p < 9 && gn < n_nodes) {
            const float2* pp = (const float2*)pos + (size_t)gn * 10 + p;
            float2 q0 = pp[0], q1 = pp[1];
            float dx = q1.x - q0.x, dy = q1.y - q0.y;
            float inv = rsqrtf(fmaf(dx, dx, fmaf(dy, dy, 1e-6f)));
            dx *= inv; dy *= inv;
            float tt  = fmaf(dx * dy, qC, fmaf(dx, qD, dy * qE));
            float var = fmaf(2.f, tt, fmaf(dx * dx, qA, fmaf(dy * dy, qB, qF)));
            float is0 = rsqrtf(var);
            ax = dx * is0; ay = dy * is0;
        }
        axs[s] = ax; ays[s] = ay;
    }

    // ---- main loop: per p, build A-frags in-register, 16 MFMA, VALU max ----
    f32x4 mx[8];
    #pragma unroll
    for (int c = 0; c < 8; ++c)
        mx[c] = (f32x4){-INFINITY, -INFINITY, -INFINITY, -INFINITY};
    const f32x4 zz = {0.f, 0.f, 0.f, 0.f};

    #pragma unroll
    for (int p = 0; p < 9; ++p) {
        const int s = p >> 2;                      // compile-time slot
        const int o = ((p & 3) << 4) | l15;        // owner lane of (node=l15, p)
        float ax = __shfl(axs[s], o, 64);
        float ay = __shfl(ays[s], o, 64);
        float is = sqrtf(fmaf(ax, ax, ay * ay));   // exact: (dx,dy) normalized

        unsigned w0[4], w1[4];
        #pragma unroll
        for (int w = 0; w < 4; ++w) {
            float4 cA = cst[2 * w], cB = cst[2 * w + 1];
            float a = fmaxf(fmaf(ax, cA.x, fmaf(ay, cA.y, fmaf(is, cA.z, cA.w))), 0.f);
            float b = fmaxf(fmaf(ax, cB.x, fmaf(ay, cB.y, fmaf(is, cB.z, cB.w))), 0.f);
            w0[w] = (f2bf(b) << 16) | f2bf(a);
            float4 cC = cst[8 + 2 * w], cD = cst[8 + 2 * w + 1];
            a = fmaxf(fmaf(ax, cC.x, fmaf(ay, cC.y, fmaf(is, cC.z, cC.w))), 0.f);
            b = fmaxf(fmaf(ax, cD.x, fmaf(ay, cD.y, fmaf(is, cD.z, cD.w))), 0.f);
            w1[w] = (f2bf(b) << 16) | f2bf(a);
        }
        bf16x8 a0 = __builtin_bit_cast(bf16x8, make_uint4(w0[0], w0[1], w0[2], w0[3]));
        bf16x8 a1 = __builtin_bit_cast(bf16x8, make_uint4(w1[0], w1[1], w1[2], w1[3]));

        #pragma unroll
        for (int c = 0; c < 8; ++c) {
            f32x4 t = __builtin_amdgcn_mfma_f32_16x16x32_bf16(a0, Bfr[c][0], zz, 0, 0, 0);
            t       = __builtin_amdgcn_mfma_f32_16x16x32_bf16(a1, Bfr[c][1], t,  0, 0, 0);
            #pragma unroll
            for (int k = 0; k < 4; ++k) mx[c][k] = fmaxf(mx[c][k], t[k]);
        }
    }

    // ---- epilogue: lane (g,l15) stores nodes g*4+jj at cols c*16+l15 ----
    int gn15 = base + l15;
    int cmb = 0;
    if (gn15 < n_nodes)
        cmb = (idx_int[gn15] * 3 + idx_turn[gn15]) * 2 + idx_tc[gn15];

    #pragma unroll
    for (int jj = 0; jj < 4; ++jj) {
        int nd  = g * 4 + jj;
        int cj  = __shfl(cmb, nd, 64);
        int gnj = base + nd;
        if (gnj < n_nodes) {
            const float* dl = ws + WS_DISC + cj * 128 + l15;
            float* op = out + (size_t)gnj * 128 + l15;
            #pragma unroll
            for (int c = 0; c < 8; ++c)
                op[c * 16] = mx[c][jj] + dl[c * 16];
        }
    }
}

extern "C" void kernel_launch(void* const* d_in, const int* in_sizes, int n_in,
                              void* d_out, int out_size, void* d_ws, size_t ws_size,
                              hipStream_t stream) {
    const float* pos  = (const float*)d_in[0];
    const int*   ii   = (const int*)  d_in[1];
    const int*   it   = (const int*)  d_in[2];
    const int*   itc  = (const int*)  d_in[3];
    const float* W1   = (const float*)d_in[4];
    const float* b1   = (const float*)d_in[5];
    const float* gam  = (const float*)d_in[6];
    const float* bet  = (const float*)d_in[7];
    const float* W2   = (const float*)d_in[8];
    const float* b2   = (const float*)d_in[9];
    const float* Ei   = (const float*)d_in[10];
    const float* Et   = (const float*)d_in[11];
    const float* Etc  = (const float*)d_in[12];
    float* out = (float*)d_out;
    float* ws  = (float*)d_ws;

    int n_nodes = in_sizes[1];                              // B*L = 65536
    int tiles   = (n_nodes + NB - 1) / NB;                  // 4096
    int blocks  = (tiles + 3) / 4;                          // 1024 (4 waves/block)

    hipLaunchKernelGGL(lane_setup_kernel, dim3(1), dim3(THREADS), 0, stream,
                       W1, b1, gam, bet, W2, b2, Ei, Et, Etc, ws);
    hipLaunchKernelGGL(lane_node_embed_mfma, dim3(blocks), dim3(THREADS), 0, stream,
                       pos, ii, it, itc, ws, out, n_nodes);
}